// Round 8
// baseline (2070.055 us; speedup 1.0000x reference)
//
#include <hip/hip_runtime.h>

// ---------------------------------------------------------------------------
// STLT forward. bf16 activations+weights, MFMA GEMMs (16x16x32 bf16), f32
// accum/epilogues. Activations flat (65536, 256) rows = (b, i, j).
// T==S==64 => qt==qs, kt==ks: Weff = Wo[:, :256] + Wo[:, 256:].
// R8: fully-fused FFN kernel (GEMM1+GELU+GEMM2+residual+LN, H never leaves
// LDS, full-K weight-chunk bursts). Other GEMMs = R5 single-buffer form.
// ---------------------------------------------------------------------------

typedef unsigned short u16;
typedef short s16;
typedef __attribute__((ext_vector_type(8))) s16 bfrag;   // 8 bf16 = 4 VGPR
typedef __attribute__((ext_vector_type(4))) float f32x4; // MFMA C/D

__device__ __forceinline__ float b2f(u16 u) {
  union { float f; unsigned int i; } v; v.i = ((unsigned int)u) << 16; return v.f;
}
__device__ __forceinline__ u16 f2b(float f) {
  union { float f; unsigned int i; } v; v.f = f;
  unsigned int x = v.i;
  return (u16)((x + 0x7FFFu + ((x >> 16) & 1u)) >> 16);
}
__device__ __forceinline__ float gelu_f(float v) {
  float u = 0.7978845608f * v * (1.0f + 0.044715f * v * v);
  float e = __expf(2.0f * u);
  return v * (1.0f - 1.0f / (e + 1.0f));
}

// async global->LDS, 16B per lane; LDS dest = base + lane*16 (wave-uniform base)
__device__ __forceinline__ void gload16(const void* g, void* l) {
  __builtin_amdgcn_global_load_lds(
      (const __attribute__((address_space(1))) unsigned int*)g,
      (__attribute__((address_space(3))) unsigned int*)l, 16, 0, 0);
}

__global__ void ws_signal(float* out, float v) { out[0] = v; }

// ---------------- weight conversion ----------------------------------------
__global__ void cvt_bf(const float* __restrict__ src, u16* __restrict__ dst, int n) {
  int i = blockIdx.x * 256 + threadIdx.x;
  if (i < n) dst[i] = f2b(src[i]);
}
__global__ void weff_bf(const float* __restrict__ Wo, u16* __restrict__ W) {
  int n = blockIdx.x, k = threadIdx.x;
  W[n * 256 + k] = f2b(Wo[n * 512 + k] + Wo[n * 512 + 256 + k]);
}

// ---------------- positional encoding --------------------------------------
__global__ void pe_kernel(float* __restrict__ pe) {
  int l = blockIdx.x, d = threadIdx.x;
  int i = d >> 1;
  float div = expf((float)(2 * i) * (-9.210340371976184f / 256.0f));
  float ang = (float)l * div;
  pe[l * 256 + d] = (d & 1) ? cosf(ang) : sinf(ang);
}

// ---------------- embedding convs (circular, K=3), f32 ---------------------
__global__ void conv_sproj(const float* __restrict__ x, const float* __restrict__ w,
                           const float* __restrict__ bias, float* __restrict__ h1) {
  int o = blockIdx.x, b = blockIdx.y, l = threadIdx.x;  // l < 96
  const float* wo = w + o * 192;
  const float* xb = x + (size_t)b * 96 * 64;
  float acc = bias[o];
#pragma unroll
  for (int k = 0; k < 3; ++k) {
    int lp = l + k - 1; if (lp < 0) lp += 96; if (lp >= 96) lp -= 96;
    const float* xr = xb + lp * 64;
    for (int c = 0; c < 64; ++c) acc = fmaf(xr[c], wo[c * 3 + k], acc);
  }
  h1[((size_t)b * 96 + o) * 96 + l] = acc;
}

__global__ void conv_scproj_t(const float* __restrict__ h1, const float* __restrict__ w,
                              const float* __restrict__ bias, float* __restrict__ h2) {
  int o = blockIdx.x, b = blockIdx.y, l = threadIdx.x;  // o<64, l<96
  const float* wo = w + o * 288;
  const float* hb = h1 + (size_t)b * 96 * 96;
  float acc = bias[o];
#pragma unroll
  for (int k = 0; k < 3; ++k) {
    int lp = l + k - 1; if (lp < 0) lp += 96; if (lp >= 96) lp -= 96;
    for (int c = 0; c < 96; ++c) acc = fmaf(hb[c * 96 + lp], wo[c * 3 + k], acc);
  }
  h2[((size_t)b * 64 + o) * 96 + l] = acc;
}

__global__ void conv_scproj_s(const float* __restrict__ h2, const float* __restrict__ w,
                              const float* __restrict__ bias, float* __restrict__ h3) {
  int o = blockIdx.x, b = blockIdx.y, l = threadIdx.x;  // o<64, l<64
  const float* wo = w + o * 288;
  const float* hb = h2 + (size_t)b * 64 * 96;
  float acc = bias[o];
#pragma unroll
  for (int k = 0; k < 3; ++k) {
    int lp = l + k - 1; if (lp < 0) lp += 64; if (lp >= 64) lp -= 64;
    for (int c = 0; c < 96; ++c) acc = fmaf(hb[lp * 96 + c], wo[c * 3 + k], acc);
  }
  h3[((size_t)b * 64 + o) * 64 + l] = acc;
}

__global__ void tok_embed(const float* __restrict__ h3, const float* __restrict__ w,
                          const float* __restrict__ bias, const float* __restrict__ pe,
                          u16* __restrict__ E) {
  int g = blockIdx.x, d = threadIdx.x;
  __shared__ float row[64];
  if (d < 64) row[d] = h3[(size_t)g * 64 + d];
  __syncthreads();
  float w0 = w[d * 3], w1 = w[d * 3 + 1], w2 = w[d * 3 + 2], bd = bias[d];
  for (int j = 0; j < 64; ++j) {
    int jm = (j + 63) & 63, jp = (j + 1) & 63;
    float v = bd + row[jm] * w0 + row[j] * w1 + row[jp] * w2 + pe[j * 256 + d];
    E[((size_t)g * 64 + j) * 256 + d] = f2b(v);
  }
}

// ---------------- MFMA GEMM (R5 single-buffer) -----------------------------
template <int ACT, int NBX>
__global__ __launch_bounds__(256) void mfma_gemm(const u16* __restrict__ A,
                                                 const u16* __restrict__ W,
                                                 const float* __restrict__ bias,
                                                 u16* __restrict__ C, int N, int K,
                                                 int nby) {
  __shared__ s16 smem[8192];
  s16* As = smem;
  s16* Bs = smem + 4096;
  constexpr int LB = (NBX == 8) ? 3 : 1;
  int f = blockIdx.x;
  int q = (NBX * nby) >> 3;
  int w = (f & 7) * q + (f >> 3);
  int bx = w & (NBX - 1), by = w >> LB;
  int t = threadIdx.x;
  int wave = t >> 6, lane = t & 63;
  int wr = wave >> 1, wc = wave & 1;
  int row0 = by * 128, col0 = bx * 128;
  int kc = (lane >> 4) & 3, rr = lane & 15;
  const u16* Ap0 = A + (size_t)(row0 + wave * 16 + rr) * K + kc * 8;
  const u16* Ap1 = A + (size_t)(row0 + (wave + 4) * 16 + rr) * K + kc * 8;
  const u16* Bp0 = W + (size_t)(col0 + wave * 16 + rr) * K + kc * 8;
  const u16* Bp1 = W + (size_t)(col0 + (wave + 4) * 16 + rr) * K + kc * 8;
  f32x4 acc[4][4];
#pragma unroll
  for (int m = 0; m < 4; ++m)
#pragma unroll
    for (int n = 0; n < 4; ++n) acc[m][n] = (f32x4){0.f, 0.f, 0.f, 0.f};
  for (int k0 = 0; k0 < K; k0 += 32) {
    gload16(Ap0 + k0, As + wave * 512);
    gload16(Ap1 + k0, As + (wave + 4) * 512);
    gload16(Bp0 + k0, Bs + wave * 512);
    gload16(Bp1 + k0, Bs + (wave + 4) * 512);
    __syncthreads();
    bfrag af[4], bf[4];
#pragma unroll
    for (int m = 0; m < 4; ++m) af[m] = *(const bfrag*)(As + ((wr * 4 + m) * 64 + lane) * 8);
#pragma unroll
    for (int n = 0; n < 4; ++n) bf[n] = *(const bfrag*)(Bs + ((wc * 4 + n) * 64 + lane) * 8);
#pragma unroll
    for (int m = 0; m < 4; ++m)
#pragma unroll
      for (int n = 0; n < 4; ++n)
        acc[m][n] = __builtin_amdgcn_mfma_f32_16x16x32_bf16(af[m], bf[n], acc[m][n], 0, 0, 0);
    __syncthreads();
  }
  s16* Cs = smem;                 // 32 x 136
  int g4 = (lane >> 4) << 2;
  int cl = lane & 15;
  float bc[4];
#pragma unroll
  for (int n = 0; n < 4; ++n) bc[n] = bias[col0 + wc * 64 + n * 16 + cl];
#pragma unroll
  for (int P = 0; P < 4; ++P) {
    __syncthreads();
    if (wr == (P >> 1)) {
#pragma unroll
      for (int mm = 0; mm < 2; ++mm) {
        int m = (P & 1) * 2 + mm;
#pragma unroll
        for (int n = 0; n < 4; ++n) {
#pragma unroll
          for (int r = 0; r < 4; ++r) {
            float v = acc[m][n][r] + bc[n];
            if (ACT == 1) v = gelu_f(v);
            Cs[(mm * 16 + g4 + r) * 136 + wc * 64 + n * 16 + cl] = (s16)f2b(v);
          }
        }
      }
    }
    __syncthreads();
#pragma unroll
    for (int it = 0; it < 2; ++it) {
      int idx = it * 256 + t;
      int lr = idx >> 4, slot = idx & 15;
      *(uint4*)(C + (size_t)(row0 + P * 32 + lr) * N + col0 + slot * 8) =
          *(const uint4*)(Cs + lr * 136 + slot * 8);
    }
  }
}

// ---------------- MFMA GEMM + bias + residual + LN (R5 single-buffer) ------
__global__ __launch_bounds__(512) void mfma_gemm_resln(const u16* __restrict__ X,
                                                       const u16* __restrict__ W,
                                                       const float* __restrict__ bias,
                                                       u16* __restrict__ R,
                                                       const float* __restrict__ lnw,
                                                       const float* __restrict__ lnb,
                                                       int K) {
  __shared__ s16 smem[12288];    // As 4096 | Bs 8192 ; epilogue Rs 8448 alias
  __shared__ float pls[32][4][2];
  s16* As = smem;
  s16* Bs = smem + 4096;
  int t = threadIdx.x;
  int wave = t >> 6, lane = t & 63;
  int wr = wave >> 2, wc = wave & 3;
  int row0 = blockIdx.x * 128;
  int kc = (lane >> 4) & 3, rr = lane & 15;
  const u16* Xp = X + (size_t)(row0 + wave * 16 + rr) * K + kc * 8;
  const u16* Wp0 = W + (size_t)(wave * 16 + rr) * K + kc * 8;
  const u16* Wp1 = W + (size_t)((wave + 8) * 16 + rr) * K + kc * 8;
  f32x4 acc[4][4];
#pragma unroll
  for (int m = 0; m < 4; ++m)
#pragma unroll
    for (int n = 0; n < 4; ++n) acc[m][n] = (f32x4){0.f, 0.f, 0.f, 0.f};
  for (int k0 = 0; k0 < K; k0 += 32) {
    gload16(Xp + k0, As + wave * 512);
    gload16(Wp0 + k0, Bs + wave * 512);
    gload16(Wp1 + k0, Bs + (wave + 8) * 512);
    __syncthreads();
    bfrag af[4], bf[4];
#pragma unroll
    for (int m = 0; m < 4; ++m) af[m] = *(const bfrag*)(As + ((wr * 4 + m) * 64 + lane) * 8);
#pragma unroll
    for (int n = 0; n < 4; ++n) bf[n] = *(const bfrag*)(Bs + ((wc * 4 + n) * 64 + lane) * 8);
#pragma unroll
    for (int m = 0; m < 4; ++m)
#pragma unroll
      for (int n = 0; n < 4; ++n)
        acc[m][n] = __builtin_amdgcn_mfma_f32_16x16x32_bf16(af[m], bf[n], acc[m][n], 0, 0, 0);
    __syncthreads();
  }
  s16* Rs = smem;                 // 32 x 264 = 8448 <= 12288
  int g4 = (lane >> 4) << 2;
  int cl = lane & 15;
  float lw[4], lb[4], bc[4];
#pragma unroll
  for (int n = 0; n < 4; ++n) {
    int col = wc * 64 + n * 16 + cl;
    bc[n] = bias[col]; lw[n] = lnw[col]; lb[n] = lnb[col];
  }
#pragma unroll
  for (int P = 0; P < 4; ++P) {
    bool own = (wr == (P >> 1));
    __syncthreads();
#pragma unroll
    for (int it = 0; it < 2; ++it) {
      int idx = it * 512 + t;
      int lr = idx >> 5, slot = idx & 31;
      *(uint4*)(Rs + lr * 264 + slot * 8) =
          *(const uint4*)(R + (size_t)(row0 + P * 32 + lr) * 256 + slot * 8);
    }
    __syncthreads();
    if (own) {
#pragma unroll
      for (int mm = 0; mm < 2; ++mm) {
        int m = (P & 1) * 2 + mm;
#pragma unroll
        for (int r = 0; r < 4; ++r) {
          int lr = mm * 16 + g4 + r;
          float s = 0.f, s2 = 0.f;
#pragma unroll
          for (int n = 0; n < 4; ++n) {
            float v = acc[m][n][r] + bc[n] +
                      b2f((u16)Rs[lr * 264 + wc * 64 + n * 16 + cl]);
            acc[m][n][r] = v;
            s += v; s2 = fmaf(v, v, s2);
          }
#pragma unroll
          for (int o = 1; o < 16; o <<= 1) { s += __shfl_xor(s, o); s2 += __shfl_xor(s2, o); }
          if (cl == 0) { pls[lr][wc][0] = s; pls[lr][wc][1] = s2; }
        }
      }
    }
    __syncthreads();
    if (own) {
#pragma unroll
      for (int mm = 0; mm < 2; ++mm) {
        int m = (P & 1) * 2 + mm;
#pragma unroll
        for (int r = 0; r < 4; ++r) {
          int lr = mm * 16 + g4 + r;
          float s = pls[lr][0][0] + pls[lr][1][0] + pls[lr][2][0] + pls[lr][3][0];
          float s2 = pls[lr][0][1] + pls[lr][1][1] + pls[lr][2][1] + pls[lr][3][1];
          float mu = s * (1.0f / 256.0f);
          float var = fmaxf(s2 * (1.0f / 256.0f) - mu * mu, 0.0f);
          float rs = rsqrtf(var + 1e-5f);
#pragma unroll
          for (int n = 0; n < 4; ++n) {
            Rs[lr * 264 + wc * 64 + n * 16 + cl] =
                (s16)f2b((acc[m][n][r] - mu) * rs * lw[n] + lb[n]);
          }
        }
      }
    }
    __syncthreads();
#pragma unroll
    for (int it = 0; it < 2; ++it) {
      int idx = it * 512 + t;
      int lr = idx >> 5, slot = idx & 31;
      *(uint4*)(R + (size_t)(row0 + P * 32 + lr) * 256 + slot * 8) =
          *(const uint4*)(Rs + lr * 264 + slot * 8);
    }
  }
}

// ---------------- FUSED FFN --------------------------------------------------
// A(M,256) <- LN( GELU(A @ C1^T + b1) @ C2^T + b2 + A ).  64 rows/block,
// 512 thr (8 waves: wr = wave>>2 over 2 row-halves, wc = wave&3 over cols).
// Per hidden chunk (8 x 128): burst-stage full-K C1 chunk (64KB) -> GEMM1
// from LDS -> GELU -> H to LDS as GEMM2-A frags -> burst-stage C2 chunk
// (64KB) -> GEMM2 accumulate. H never touches global memory.
__global__ __launch_bounds__(512) void ffn_fused(u16* __restrict__ A,
                                                 const u16* __restrict__ C1,
                                                 const float* __restrict__ b1,
                                                 const u16* __restrict__ C2,
                                                 const float* __restrict__ b2,
                                                 const float* __restrict__ lnw,
                                                 const float* __restrict__ lnb) {
  __shared__ s16 XF[16384];   // X frags: (ks*4+m)*512, ks<8, m<4
  __shared__ s16 BF[32768];   // B frags (both GEMMs) / epilogue Rs (64x264)
  __shared__ s16 HF[8192];    // H frags: (ks2*4+m2)*512, ks2<4, m2<4
  __shared__ float pls[64][4][2];
  int t = threadIdx.x;
  int wave = t >> 6, lane = t & 63;
  int wr = wave >> 2, wc = wave & 3;
  int row0 = blockIdx.x * 64;
  int rr = lane & 15, kc = lane >> 4;        // staging coords (kc in 0..3)
  int g4 = (lane >> 4) << 2, cl = lane & 15; // C/D coords

  // stage X once: frag f = wave*4+i -> (ks = f>>2, m = f&3)
#pragma unroll
  for (int i = 0; i < 4; ++i) {
    int f = wave * 4 + i;
    int ks = f >> 2, m = f & 3;
    gload16(A + (size_t)(row0 + m * 16 + rr) * 256 + ks * 32 + kc * 8, XF + f * 512);
  }

  f32x4 acc2[2][4];
#pragma unroll
  for (int mi = 0; mi < 2; ++mi)
#pragma unroll
    for (int nj = 0; nj < 4; ++nj) acc2[mi][nj] = (f32x4){0.f, 0.f, 0.f, 0.f};

  for (int hc = 0; hc < 8; ++hc) {
    // ---- stage B1 = C1[hc*128..+128][:] as frags f=(ks<<3)|n (8 per wave)
#pragma unroll
    for (int i = 0; i < 8; ++i) {
      int f = i * 8 + wave;
      int ks = f >> 3, n = f & 7;
      gload16(C1 + (size_t)(hc * 128 + n * 16 + rr) * 256 + ks * 32 + kc * 8,
              BF + f * 512);
    }
    __syncthreads();
    // ---- GEMM1: wave output 32x32 of the 64x128 H chunk
    f32x4 acc1[2][2];
#pragma unroll
    for (int mi = 0; mi < 2; ++mi)
#pragma unroll
      for (int ni = 0; ni < 2; ++ni) acc1[mi][ni] = (f32x4){0.f, 0.f, 0.f, 0.f};
#pragma unroll
    for (int ks = 0; ks < 8; ++ks) {
      bfrag a0 = *(const bfrag*)(XF + ((ks * 4 + wr * 2 + 0) * 64 + lane) * 8);
      bfrag a1 = *(const bfrag*)(XF + ((ks * 4 + wr * 2 + 1) * 64 + lane) * 8);
      bfrag b0 = *(const bfrag*)(BF + ((ks * 8 + wc * 2 + 0) * 64 + lane) * 8);
      bfrag b1f = *(const bfrag*)(BF + ((ks * 8 + wc * 2 + 1) * 64 + lane) * 8);
      acc1[0][0] = __builtin_amdgcn_mfma_f32_16x16x32_bf16(a0, b0, acc1[0][0], 0, 0, 0);
      acc1[0][1] = __builtin_amdgcn_mfma_f32_16x16x32_bf16(a0, b1f, acc1[0][1], 0, 0, 0);
      acc1[1][0] = __builtin_amdgcn_mfma_f32_16x16x32_bf16(a1, b0, acc1[1][0], 0, 0, 0);
      acc1[1][1] = __builtin_amdgcn_mfma_f32_16x16x32_bf16(a1, b1f, acc1[1][1], 0, 0, 0);
    }
    // ---- bias + GELU + write H frags (GEMM2-A layout); ks2 = wc here
#pragma unroll
    for (int ni = 0; ni < 2; ++ni) {
      float bcol = b1[hc * 128 + wc * 32 + ni * 16 + cl];
      int kc2 = ni * 2 + (cl >> 3);
      int e = cl & 7;
#pragma unroll
      for (int mi = 0; mi < 2; ++mi) {
        int fbase = (wc * 4 + wr * 2 + mi) * 512;
#pragma unroll
        for (int r = 0; r < 4; ++r) {
          float v = gelu_f(acc1[mi][ni][r] + bcol);
          HF[fbase + (g4 + r + kc2 * 16) * 8 + e] = (s16)f2b(v);
        }
      }
    }
    __syncthreads();
    // ---- stage B2 = C2[:, hc*128..+128] as frags f=(ks2<<4)|n2 (8 per wave)
#pragma unroll
    for (int i = 0; i < 8; ++i) {
      int f = i * 8 + wave;
      int ks2 = f >> 4, n2 = f & 15;
      gload16(C2 + (size_t)(n2 * 16 + rr) * 1024 + hc * 128 + ks2 * 32 + kc * 8,
              BF + f * 512);
    }
    __syncthreads();
    // ---- GEMM2: wave output 32x64 of the 64x256 result
#pragma unroll
    for (int ks2 = 0; ks2 < 4; ++ks2) {
      bfrag a0 = *(const bfrag*)(HF + ((ks2 * 4 + wr * 2 + 0) * 64 + lane) * 8);
      bfrag a1 = *(const bfrag*)(HF + ((ks2 * 4 + wr * 2 + 1) * 64 + lane) * 8);
#pragma unroll
      for (int nj = 0; nj < 4; ++nj) {
        bfrag bb = *(const bfrag*)(BF + ((ks2 * 16 + wc * 4 + nj) * 64 + lane) * 8);
        acc2[0][nj] = __builtin_amdgcn_mfma_f32_16x16x32_bf16(a0, bb, acc2[0][nj], 0, 0, 0);
        acc2[1][nj] = __builtin_amdgcn_mfma_f32_16x16x32_bf16(a1, bb, acc2[1][nj], 0, 0, 0);
      }
    }
    __syncthreads();
  }

  // ---- epilogue: residual + LN over full 256-col rows ----
  s16* Rs = BF;  // 64 x 264 u16 = 16896 <= 32768
#pragma unroll
  for (int it = 0; it < 4; ++it) {
    int idx = it * 512 + t;
    int lr = idx >> 5, slot = idx & 31;
    *(uint4*)(Rs + lr * 264 + slot * 8) =
        *(const uint4*)(A + (size_t)(row0 + lr) * 256 + slot * 8);
  }
  __syncthreads();
  float lw[4], lb[4], bc2[4];
#pragma unroll
  for (int nj = 0; nj < 4; ++nj) {
    int col = wc * 64 + nj * 16 + cl;
    bc2[nj] = b2[col]; lw[nj] = lnw[col]; lb[nj] = lnb[col];
  }
#pragma unroll
  for (int mi = 0; mi < 2; ++mi) {
#pragma unroll
    for (int r = 0; r < 4; ++r) {
      int row = wr * 32 + mi * 16 + g4 + r;
      float s = 0.f, s2 = 0.f;
#pragma unroll
      for (int nj = 0; nj < 4; ++nj) {
        int col = wc * 64 + nj * 16 + cl;
        float v = acc2[mi][nj][r] + bc2[nj] + b2f((u16)Rs[row * 264 + col]);
        acc2[mi][nj][r] = v;
        s += v; s2 = fmaf(v, v, s2);
      }
#pragma unroll
      for (int o = 1; o < 16; o <<= 1) { s += __shfl_xor(s, o); s2 += __shfl_xor(s2, o); }
      if (cl == 0) { pls[row][wc][0] = s; pls[row][wc][1] = s2; }
    }
  }
  __syncthreads();
#pragma unroll
  for (int mi = 0; mi < 2; ++mi) {
#pragma unroll
    for (int r = 0; r < 4; ++r) {
      int row = wr * 32 + mi * 16 + g4 + r;
      float s = pls[row][0][0] + pls[row][1][0] + pls[row][2][0] + pls[row][3][0];
      float s2 = pls[row][0][1] + pls[row][1][1] + pls[row][2][1] + pls[row][3][1];
      float mu = s * (1.0f / 256.0f);
      float var = fmaxf(s2 * (1.0f / 256.0f) - mu * mu, 0.0f);
      float rs = rsqrtf(var + 1e-5f);
#pragma unroll
      for (int nj = 0; nj < 4; ++nj) {
        int col = wc * 64 + nj * 16 + cl;
        Rs[row * 264 + col] = (s16)f2b((acc2[mi][nj][r] - mu) * rs * lw[nj] + lb[nj]);
      }
    }
  }
  __syncthreads();
#pragma unroll
  for (int it = 0; it < 4; ++it) {
    int idx = it * 512 + t;
    int lr = idx >> 5, slot = idx & 31;
    *(uint4*)(A + (size_t)(row0 + lr) * 256 + slot * 8) =
        *(const uint4*)(Rs + lr * 264 + slot * 8);
  }
}

// ---------------- pooled linear attention (in-place on Q), LDS-staged ------
template <int CROSS, int CAUSAL>
__global__ __launch_bounds__(512) void lin_attn(u16* __restrict__ Q,
                                                const u16* __restrict__ KP) {
  __shared__ u16 qs[64 * 264];
  __shared__ float kpool[16][260];
  int p = blockIdx.x, t = threadIdx.x;
  u16* Qg = Q + (size_t)p * 16384;
#pragma unroll
  for (int i = 0; i < 4; ++i) {
    int idx = i * 512 + t;
    int row = idx >> 5, slot = idx & 31;
    *(uint4*)(qs + row * 264 + slot * 8) = *(const uint4*)(Qg + row * 256 + slot * 8);
  }
  __syncthreads();
  if (CROSS) {
    for (int idx = t; idx < 4096; idx += 512) {
      int s = idx >> 8, d = idx & 255;
      kpool[s][d] = b2f(KP[((size_t)p * 16 + s) * 256 + d]);
    }
  } else {
    for (int idx = t; idx < 4096; idx += 512) {
      int s = idx >> 8, d = idx & 255;
      const u16* b0 = qs + (4 * s) * 264 + d;
      kpool[s][d] = 0.25f * (b2f(b0[0]) + b2f(b0[264]) + b2f(b0[528]) + b2f(b0[792]));
    }
  }
  __syncthreads();
  int h = t >> 6, l = t & 63;
  u16* q = qs + l * 264 + h * 32;
  float qr[32];
#pragma unroll
  for (int e = 0; e < 32; e += 4) {
    ushort4 v = *(const ushort4*)&q[e];
    qr[e] = b2f(v.x); qr[e + 1] = b2f(v.y); qr[e + 2] = b2f(v.z); qr[e + 3] = b2f(v.w);
  }
  float sc[16], mx = -INFINITY;
#pragma unroll
  for (int s = 0; s < 16; ++s) {
    const float* kp = &kpool[s][h * 32];
    float d = 0.f;
#pragma unroll
    for (int e = 0; e < 32; ++e) d = fmaf(qr[e], kp[e], d);
    d *= 0.17677669529663687f;
    if (CAUSAL && s > l) d = -INFINITY;
    sc[s] = d; mx = fmaxf(mx, d);
  }
  float sum = 0.f;
#pragma unroll
  for (int s = 0; s < 16; ++s) { sc[s] = expf(sc[s] - mx); sum += sc[s]; }
  float inv = 1.0f / sum;
  float o[32] = {};
#pragma unroll
  for (int s = 0; s < 16; ++s) {
    float a = sc[s] * inv;
    const float* vp = &kpool[s][h * 32];
#pragma unroll
    for (int e = 0; e < 32; ++e) o[e] = fmaf(a, vp[e], o[e]);
  }
#pragma unroll
  for (int e = 0; e < 32; e += 4) {
    ushort4 v;
    v.x = f2b(o[e]); v.y = f2b(o[e + 1]); v.z = f2b(o[e + 2]); v.w = f2b(o[e + 3]);
    *(ushort4*)&q[e] = v;
  }
  __syncthreads();
#pragma unroll
  for (int i = 0; i < 4; ++i) {
    int idx = i * 512 + t;
    int row = idx >> 5, slot = idx & 31;
    *(uint4*)(Qg + row * 256 + slot * 8) = *(const uint4*)(qs + row * 264 + slot * 8);
  }
}

// ---------------- plain LayerNorm (in place), bf16 -------------------------
__global__ __launch_bounds__(256) void ln_bf(u16* __restrict__ X,
                                             const float* __restrict__ w,
                                             const float* __restrict__ b) {
  int lane = threadIdx.x & 63, wv = threadIdx.x >> 6;
  size_t row = (size_t)blockIdx.x * 4 + wv;
  size_t off = row * 256 + lane * 4;
  ushort4 xv = *(const ushort4*)(X + off);
  float v0 = b2f(xv.x), v1 = b2f(xv.y), v2 = b2f(xv.z), v3 = b2f(xv.w);
  float s = v0 + v1 + v2 + v3;
  float s2 = v0 * v0 + v1 * v1 + v2 * v2 + v3 * v3;
#pragma unroll
  for (int o = 32; o; o >>= 1) { s += __shfl_xor(s, o); s2 += __shfl_xor(s2, o); }
  float mu = s * (1.0f / 256.0f);
  float var = fmaxf(s2 * (1.0f / 256.0f) - mu * mu, 0.0f);
  float rs = rsqrtf(var + 1e-5f);
  float4 w4 = *(const float4*)(w + lane * 4);
  float4 b4 = *(const float4*)(b + lane * 4);
  ushort4 o4;
  o4.x = f2b((v0 - mu) * rs * w4.x + b4.x);
  o4.y = f2b((v1 - mu) * rs * w4.y + b4.y);
  o4.z = f2b((v2 - mu) * rs * w4.z + b4.z);
  o4.w = f2b((v3 - mu) * rs * w4.w + b4.w);
  *(ushort4*)(X + off) = o4;
}

// ---------------- pool over j (4:1) ----------------------------------------
__global__ void pool_bf(const u16* __restrict__ A, u16* __restrict__ P) {
  int r = blockIdx.x, d = threadIdx.x;
  int g = r >> 4, s = r & 15;
  const u16* src = A + ((size_t)g * 64 + 4 * (size_t)s) * 256 + d;
  float v = 0.25f * (b2f(src[0]) + b2f(src[256]) + b2f(src[512]) + b2f(src[768]));
  P[(size_t)r * 256 + d] = f2b(v);
}

// ---------------- mean over j + final projection + slice -------------------
__global__ __launch_bounds__(256) void mean_proj_bf(const u16* __restrict__ X,
                                                    const float* __restrict__ pw,
                                                    const float* __restrict__ pb,
                                                    float* __restrict__ out) {
  int bid = blockIdx.x;
  int b = bid >> 5, ii = bid & 31;
  int i = 32 + ii;
  __shared__ float md[256];
  int d = threadIdx.x;
  const u16* base = X + ((size_t)b * 64 + i) * 64 * 256 + d;
  float s = 0.f;
  for (int j = 0; j < 64; ++j) s += b2f(base[(size_t)j * 256]);
  md[d] = s * (1.0f / 64.0f);
  __syncthreads();
  if (d < 64) {
    float acc = pb[d];
    const float* wr = pw + d * 256;
    for (int k = 0; k < 256; ++k) acc = fmaf(md[k], wr[k], acc);
    out[((size_t)b * 32 + ii) * 64 + d] = acc;
  }
}

// ---------------------------------------------------------------------------
extern "C" void kernel_launch(void* const* d_in, const int* in_sizes, int n_in,
                              void* d_out, int out_size, void* d_ws, size_t ws_size,
                              hipStream_t stream) {
  (void)in_sizes; (void)out_size;
  if (n_in < 50) return;

  const float* x_enc = (const float*)d_in[0];
  const float* x_dec = (const float*)d_in[1];
  const float* enc_sproj_w = (const float*)d_in[2];
  const float* enc_sproj_b = (const float*)d_in[3];
  const float* enc_scproj_w = (const float*)d_in[4];
  const float* enc_scproj_b = (const float*)d_in[5];
  const float* enc_tok_w = (const float*)d_in[6];
  const float* enc_tok_b = (const float*)d_in[7];
  const float* dec_sproj_w = (const float*)d_in[8];
  const float* dec_sproj_b = (const float*)d_in[9];
  const float* dec_scproj_w = (const float*)d_in[10];
  const float* dec_scproj_b = (const float*)d_in[11];
  const float* dec_tok_w = (const float*)d_in[12];
  const float* dec_tok_b = (const float*)d_in[13];
  const float* e_Wq = (const float*)d_in[14];
  const float* e_bq = (const float*)d_in[15];
  const float* e_Wo = (const float*)d_in[16];
  const float* e_bo = (const float*)d_in[17];
  const float* e_c1w = (const float*)d_in[18];
  const float* e_c1b = (const float*)d_in[19];
  const float* e_c2w = (const float*)d_in[20];
  const float* e_c2b = (const float*)d_in[21];
  const float* e_ln1w = (const float*)d_in[22];
  const float* e_ln1b = (const float*)d_in[23];
  const float* e_ln2w = (const float*)d_in[24];
  const float* e_ln2b = (const float*)d_in[25];
  const float* enc_norm_w = (const float*)d_in[26];
  const float* enc_norm_b = (const float*)d_in[27];
  const float* d_sWq = (const float*)d_in[28];
  const float* d_sbq = (const float*)d_in[29];
  const float* d_sWo = (const float*)d_in[30];
  const float* d_sbo = (const float*)d_in[31];
  const float* d_cWq = (const float*)d_in[32];
  const float* d_cbq = (const float*)d_in[33];
  const float* d_cWo = (const float*)d_in[34];
  const float* d_cbo = (const float*)d_in[35];
  const float* d_c1w = (const float*)d_in[36];
  const float* d_c1b = (const float*)d_in[37];
  const float* d_c2w = (const float*)d_in[38];
  const float* d_c2b = (const float*)d_in[39];
  const float* d_ln1w = (const float*)d_in[40];
  const float* d_ln1b = (const float*)d_in[41];
  const float* d_ln2w = (const float*)d_in[42];
  const float* d_ln2b = (const float*)d_in[43];
  const float* d_ln3w = (const float*)d_in[44];
  const float* d_ln3b = (const float*)d_in[45];
  const float* dec_norm_w = (const float*)d_in[46];
  const float* dec_norm_b = (const float*)d_in[47];
  const float* proj_w = (const float*)d_in[48];
  const float* proj_b = (const float*)d_in[49];

  // ---- workspace layout ----
  const size_t ACT = 16777216;    // 65536*256
  const size_t POOLE = 4194304;   // 16384*256
  const size_t WBN = 3538944;     // bf16 weight pool elements
  size_t base_need = (3 * ACT + 2 * POOLE + WBN) * 2 +
                     (size_t)(16384 + 147456 + 98304 + 65536) * 4;
  if (ws_size < base_need) {
    ws_signal<<<1, 1, 0, stream>>>((float*)d_out, (float)(ws_size >> 20));
    return;
  }
  char* wsb = (char*)d_ws;
  u16* A_enc = (u16*)wsb;  wsb += ACT * 2;
  u16* A_dec = (u16*)wsb;  wsb += ACT * 2;
  u16* T1 = (u16*)wsb;     wsb += ACT * 2;   // attn scratch
  u16* PA = (u16*)wsb;     wsb += POOLE * 2;
  u16* PK = (u16*)wsb;     wsb += POOLE * 2;
  u16* WB = (u16*)wsb;     wsb += WBN * 2;
  float* PE = (float*)wsb;  wsb += 16384 * 4;
  float* EH1 = (float*)wsb; wsb += 147456 * 4;
  float* EH2 = (float*)wsb; wsb += 98304 * 4;
  float* EH3 = (float*)wsb; wsb += 65536 * 4;

  // bf16 weight pool offsets (elements)
  u16* eWq = WB;                    // 3 x 65536
  u16* eWeff = WB + 196608;         // 3 x 65536
  u16* eC1 = WB + 393216;           // 3 x 262144
  u16* eC2 = WB + 1179648;          // 3 x 262144
  u16* dB = WB + 1966080;
  u16* dsWq = dB;                   // 2 x 65536
  u16* dsWeff = dB + 131072;        // 2 x 65536
  u16* dcWq = dB + 262144;          // 2 x 65536
  u16* dcWeff = dB + 393216;        // 2 x 65536
  u16* dC1 = dB + 524288;           // 2 x 262144
  u16* dC2 = dB + 1048576;          // 2 x 262144

  // ---- weight conversion ----
  cvt_bf<<<768, 256, 0, stream>>>(e_Wq, eWq, 196608);
  cvt_bf<<<3072, 256, 0, stream>>>(e_c1w, eC1, 786432);
  cvt_bf<<<3072, 256, 0, stream>>>(e_c2w, eC2, 786432);
  cvt_bf<<<512, 256, 0, stream>>>(d_sWq, dsWq, 131072);
  cvt_bf<<<512, 256, 0, stream>>>(d_cWq, dcWq, 131072);
  cvt_bf<<<2048, 256, 0, stream>>>(d_c1w, dC1, 524288);
  cvt_bf<<<2048, 256, 0, stream>>>(d_c2w, dC2, 524288);
  for (int i = 0; i < 3; ++i)
    weff_bf<<<256, 256, 0, stream>>>(e_Wo + (size_t)i * 131072, eWeff + (size_t)i * 65536);
  for (int i = 0; i < 2; ++i) {
    weff_bf<<<256, 256, 0, stream>>>(d_sWo + (size_t)i * 131072, dsWeff + (size_t)i * 65536);
    weff_bf<<<256, 256, 0, stream>>>(d_cWo + (size_t)i * 131072, dcWeff + (size_t)i * 65536);
  }

  pe_kernel<<<64, 256, 0, stream>>>(PE);

  // ---- encoder embedding ----
  conv_sproj<<<dim3(96, 16), 96, 0, stream>>>(x_enc, enc_sproj_w, enc_sproj_b, EH1);
  conv_scproj_t<<<dim3(64, 16), 96, 0, stream>>>(EH1, enc_scproj_w, enc_scproj_b, EH2);
  conv_scproj_s<<<dim3(64, 16), 64, 0, stream>>>(EH2, enc_scproj_w, enc_scproj_b, EH3);
  tok_embed<<<1024, 256, 0, stream>>>(EH3, enc_tok_w, enc_tok_b, PE, A_enc);

  // ---- encoder layers ----
  for (int i = 0; i < 3; ++i) {
    mfma_gemm<0, 2><<<1024, 256, 0, stream>>>(A_enc, eWq + (size_t)i * 65536,
                                              e_bq + i * 256, T1, 256, 256, 512);
    lin_attn<0, 0><<<1024, 512, 0, stream>>>(T1, nullptr);
    mfma_gemm_resln<<<512, 512, 0, stream>>>(T1, eWeff + (size_t)i * 65536, e_bo + i * 256,
                                             A_enc, e_ln1w + i * 256, e_ln1b + i * 256, 256);
    ffn_fused<<<1024, 512, 0, stream>>>(A_enc, eC1 + (size_t)i * 262144, e_c1b + i * 1024,
                                        eC2 + (size_t)i * 262144, e_c2b + i * 256,
                                        e_ln2w + i * 256, e_ln2b + i * 256);
  }
  ln_bf<<<16384, 256, 0, stream>>>(A_enc, enc_norm_w, enc_norm_b);
  pool_bf<<<16384, 256, 0, stream>>>(A_enc, PA);

  // ---- decoder embedding ----
  conv_sproj<<<dim3(96, 16), 96, 0, stream>>>(x_dec, dec_sproj_w, dec_sproj_b, EH1);
  conv_scproj_t<<<dim3(64, 16), 96, 0, stream>>>(EH1, dec_scproj_w, dec_scproj_b, EH2);
  conv_scproj_s<<<dim3(64, 16), 64, 0, stream>>>(EH2, dec_scproj_w, dec_scproj_b, EH3);
  tok_embed<<<1024, 256, 0, stream>>>(EH3, dec_tok_w, dec_tok_b, PE, A_dec);

  // ---- decoder layers ----
  for (int i = 0; i < 2; ++i) {
    mfma_gemm<0, 2><<<1024, 256, 0, stream>>>(A_dec, dsWq + (size_t)i * 65536,
                                              d_sbq + i * 256, T1, 256, 256, 512);
    lin_attn<0, 1><<<1024, 512, 0, stream>>>(T1, nullptr);
    mfma_gemm_resln<<<512, 512, 0, stream>>>(T1, dsWeff + (size_t)i * 65536, d_sbo + i * 256,
                                             A_dec, d_ln1w + i * 256, d_ln1b + i * 256, 256);
    mfma_gemm<0, 2><<<1024, 256, 0, stream>>>(A_dec, dcWq + (size_t)i * 65536,
                                              d_cbq + i * 256, T1, 256, 256, 512);
    mfma_gemm<0, 2><<<256, 256, 0, stream>>>(PA, dcWq + (size_t)i * 65536,
                                             d_cbq + i * 256, PK, 256, 256, 128);
    lin_attn<1, 0><<<1024, 512, 0, stream>>>(T1, PK);
    mfma_gemm_resln<<<512, 512, 0, stream>>>(T1, dcWeff + (size_t)i * 65536, d_cbo + i * 256,
                                             A_dec, d_ln2w + i * 256, d_ln2b + i * 256, 256);
    ffn_fused<<<1024, 512, 0, stream>>>(A_dec, dC1 + (size_t)i * 262144, d_c1b + i * 1024,
                                        dC2 + (size_t)i * 262144, d_c2b + i * 256,
                                        d_ln3w + i * 256, d_ln3b + i * 256);
  }
  ln_bf<<<16384, 256, 0, stream>>>(A_dec, dec_norm_w, dec_norm_b);

  mean_proj_bf<<<512, 256, 0, stream>>>(A_dec, proj_w, proj_b, (float*)d_out);
}

// Round 9
// 1791.719 us; speedup vs baseline: 1.1553x; 1.1553x over previous
//
#include <hip/hip_runtime.h>

// ---------------------------------------------------------------------------
// STLT forward. bf16 activations+weights, MFMA GEMMs (16x16x32 bf16), f32
// accum/epilogues. Activations flat (65536, 256) rows = (b, i, j).
// T==S==64 => qt==qs, kt==ks: Weff = Wo[:, :256] + Wo[:, 256:].
// R9: counted-vmcnt 2-phase K-loop (T4): raw s_barrier + s_waitcnt vmcnt(N),
// never draining to 0 mid-loop; prefetch stays in flight across barriers.
// FFN back to two-kernel R5 form (fused FFN of R8 regressed: 1-block/CU +
// 2.1M LDS bank conflicts).
// ---------------------------------------------------------------------------

typedef unsigned short u16;
typedef short s16;
typedef __attribute__((ext_vector_type(8))) s16 bfrag;   // 8 bf16 = 4 VGPR
typedef __attribute__((ext_vector_type(4))) float f32x4; // MFMA C/D

__device__ __forceinline__ float b2f(u16 u) {
  union { float f; unsigned int i; } v; v.i = ((unsigned int)u) << 16; return v.f;
}
__device__ __forceinline__ u16 f2b(float f) {
  union { float f; unsigned int i; } v; v.f = f;
  unsigned int x = v.i;
  return (u16)((x + 0x7FFFu + ((x >> 16) & 1u)) >> 16);
}
__device__ __forceinline__ float gelu_f(float v) {
  float u = 0.7978845608f * v * (1.0f + 0.044715f * v * v);
  float e = __expf(2.0f * u);
  return v * (1.0f - 1.0f / (e + 1.0f));
}

// async global->LDS, 16B per lane; LDS dest = base + lane*16 (wave-uniform base)
__device__ __forceinline__ void gload16(const void* g, void* l) {
  __builtin_amdgcn_global_load_lds(
      (const __attribute__((address_space(1))) unsigned int*)g,
      (__attribute__((address_space(3))) unsigned int*)l, 16, 0, 0);
}

__global__ void ws_signal(float* out, float v) { out[0] = v; }

// ---------------- weight conversion ----------------------------------------
__global__ void cvt_bf(const float* __restrict__ src, u16* __restrict__ dst, int n) {
  int i = blockIdx.x * 256 + threadIdx.x;
  if (i < n) dst[i] = f2b(src[i]);
}
__global__ void weff_bf(const float* __restrict__ Wo, u16* __restrict__ W) {
  int n = blockIdx.x, k = threadIdx.x;
  W[n * 256 + k] = f2b(Wo[n * 512 + k] + Wo[n * 512 + 256 + k]);
}

// ---------------- positional encoding --------------------------------------
__global__ void pe_kernel(float* __restrict__ pe) {
  int l = blockIdx.x, d = threadIdx.x;
  int i = d >> 1;
  float div = expf((float)(2 * i) * (-9.210340371976184f / 256.0f));
  float ang = (float)l * div;
  pe[l * 256 + d] = (d & 1) ? cosf(ang) : sinf(ang);
}

// ---------------- embedding convs (circular, K=3), f32 ---------------------
__global__ void conv_sproj(const float* __restrict__ x, const float* __restrict__ w,
                           const float* __restrict__ bias, float* __restrict__ h1) {
  int o = blockIdx.x, b = blockIdx.y, l = threadIdx.x;  // l < 96
  const float* wo = w + o * 192;
  const float* xb = x + (size_t)b * 96 * 64;
  float acc = bias[o];
#pragma unroll
  for (int k = 0; k < 3; ++k) {
    int lp = l + k - 1; if (lp < 0) lp += 96; if (lp >= 96) lp -= 96;
    const float* xr = xb + lp * 64;
    for (int c = 0; c < 64; ++c) acc = fmaf(xr[c], wo[c * 3 + k], acc);
  }
  h1[((size_t)b * 96 + o) * 96 + l] = acc;
}

__global__ void conv_scproj_t(const float* __restrict__ h1, const float* __restrict__ w,
                              const float* __restrict__ bias, float* __restrict__ h2) {
  int o = blockIdx.x, b = blockIdx.y, l = threadIdx.x;  // o<64, l<96
  const float* wo = w + o * 288;
  const float* hb = h1 + (size_t)b * 96 * 96;
  float acc = bias[o];
#pragma unroll
  for (int k = 0; k < 3; ++k) {
    int lp = l + k - 1; if (lp < 0) lp += 96; if (lp >= 96) lp -= 96;
    for (int c = 0; c < 96; ++c) acc = fmaf(hb[c * 96 + lp], wo[c * 3 + k], acc);
  }
  h2[((size_t)b * 64 + o) * 96 + l] = acc;
}

__global__ void conv_scproj_s(const float* __restrict__ h2, const float* __restrict__ w,
                              const float* __restrict__ bias, float* __restrict__ h3) {
  int o = blockIdx.x, b = blockIdx.y, l = threadIdx.x;  // o<64, l<64
  const float* wo = w + o * 288;
  const float* hb = h2 + (size_t)b * 64 * 96;
  float acc = bias[o];
#pragma unroll
  for (int k = 0; k < 3; ++k) {
    int lp = l + k - 1; if (lp < 0) lp += 64; if (lp >= 64) lp -= 64;
    for (int c = 0; c < 96; ++c) acc = fmaf(hb[lp * 96 + c], wo[c * 3 + k], acc);
  }
  h3[((size_t)b * 64 + o) * 64 + l] = acc;
}

__global__ void tok_embed(const float* __restrict__ h3, const float* __restrict__ w,
                          const float* __restrict__ bias, const float* __restrict__ pe,
                          u16* __restrict__ E) {
  int g = blockIdx.x, d = threadIdx.x;
  __shared__ float row[64];
  if (d < 64) row[d] = h3[(size_t)g * 64 + d];
  __syncthreads();
  float w0 = w[d * 3], w1 = w[d * 3 + 1], w2 = w[d * 3 + 2], bd = bias[d];
  for (int j = 0; j < 64; ++j) {
    int jm = (j + 63) & 63, jp = (j + 1) & 63;
    float v = bd + row[jm] * w0 + row[j] * w1 + row[jp] * w2 + pe[j * 256 + d];
    E[((size_t)g * 64 + j) * 256 + d] = f2b(v);
  }
}

// ---------------- MFMA GEMM: C(M,N) = A(M,K) @ W(N,K)^T + bias -------------
// 128x128 tile, 256 thr (4 waves 2x2). Counted-vmcnt 2-phase K-loop.
// Per K-step: wait vmcnt(4) -> bar -> ds_read -> lgkmcnt(0) -> bar ->
// STAGE(k+2) -> MFMA. Requires nk even (K % 64 == 0).
template <int ACT, int NBX>
__global__ __launch_bounds__(256) void mfma_gemm(const u16* __restrict__ A,
                                                 const u16* __restrict__ W,
                                                 const float* __restrict__ bias,
                                                 u16* __restrict__ C, int N, int K,
                                                 int nby) {
  __shared__ s16 smem[16384];
  s16* A0 = smem;        s16* A1 = smem + 4096;
  s16* B0 = smem + 8192; s16* B1 = smem + 12288;
  constexpr int LB = (NBX == 8) ? 3 : 1;
  int f = blockIdx.x;
  int q = (NBX * nby) >> 3;
  int w = (f & 7) * q + (f >> 3);
  int bx = w & (NBX - 1), by = w >> LB;
  int t = threadIdx.x;
  int wave = t >> 6, lane = t & 63;
  int wr = wave >> 1, wc = wave & 1;
  int row0 = by * 128, col0 = bx * 128;
  int kc = (lane >> 4) & 3, rr = lane & 15;
  const u16* Ap0 = A + (size_t)(row0 + wave * 16 + rr) * K + kc * 8;
  const u16* Ap1 = A + (size_t)(row0 + (wave + 4) * 16 + rr) * K + kc * 8;
  const u16* Bp0 = W + (size_t)(col0 + wave * 16 + rr) * K + kc * 8;
  const u16* Bp1 = W + (size_t)(col0 + (wave + 4) * 16 + rr) * K + kc * 8;
  f32x4 acc[4][4];
#pragma unroll
  for (int m = 0; m < 4; ++m)
#pragma unroll
    for (int n = 0; n < 4; ++n) acc[m][n] = (f32x4){0.f, 0.f, 0.f, 0.f};

  auto STAGE = [&](s16* a, s16* b, int kidx) {
    int k0 = kidx * 32;
    gload16(Ap0 + k0, a + wave * 512);
    gload16(Ap1 + k0, a + (wave + 4) * 512);
    gload16(Bp0 + k0, b + wave * 512);
    gload16(Bp1 + k0, b + (wave + 4) * 512);
  };
  int nk = K >> 5;
  auto STEP = [&](const s16* a, const s16* b, s16* sa, s16* sb, int ks) {
    if (ks + 1 < nk) asm volatile("s_waitcnt vmcnt(4)" ::: "memory");
    else             asm volatile("s_waitcnt vmcnt(0)" ::: "memory");
    __builtin_amdgcn_sched_barrier(0);
    __builtin_amdgcn_s_barrier();
    __builtin_amdgcn_sched_barrier(0);
    bfrag af[4], bf[4];
#pragma unroll
    for (int m = 0; m < 4; ++m) af[m] = *(const bfrag*)(a + ((wr * 4 + m) * 64 + lane) * 8);
#pragma unroll
    for (int n = 0; n < 4; ++n) bf[n] = *(const bfrag*)(b + ((wc * 4 + n) * 64 + lane) * 8);
    asm volatile("s_waitcnt lgkmcnt(0)" ::: "memory");
    __builtin_amdgcn_sched_barrier(0);
    __builtin_amdgcn_s_barrier();
    __builtin_amdgcn_sched_barrier(0);
    if (ks + 2 < nk) STAGE(sa, sb, ks + 2);
#pragma unroll
    for (int m = 0; m < 4; ++m)
#pragma unroll
      for (int n = 0; n < 4; ++n)
        acc[m][n] = __builtin_amdgcn_mfma_f32_16x16x32_bf16(af[m], bf[n], acc[m][n], 0, 0, 0);
  };

  STAGE(A0, B0, 0);
  STAGE(A1, B1, 1);
  for (int ks = 0; ks < nk; ks += 2) {
    STEP(A0, B0, A0, B0, ks);
    STEP(A1, B1, A1, B1, ks + 1);
  }
  // ---- epilogue: LDS-staged coalesced stores, 4 passes of 32 rows ----
  s16* Cs = smem;                 // 32 x 136 u16
  int g4 = (lane >> 4) << 2;
  int cl = lane & 15;
  float bc[4];
#pragma unroll
  for (int n = 0; n < 4; ++n) bc[n] = bias[col0 + wc * 64 + n * 16 + cl];
#pragma unroll
  for (int P = 0; P < 4; ++P) {
    __syncthreads();
    if (wr == (P >> 1)) {
#pragma unroll
      for (int mm = 0; mm < 2; ++mm) {
        int m = (P & 1) * 2 + mm;
#pragma unroll
        for (int n = 0; n < 4; ++n) {
#pragma unroll
          for (int r = 0; r < 4; ++r) {
            float v = acc[m][n][r] + bc[n];
            if (ACT == 1) v = gelu_f(v);
            Cs[(mm * 16 + g4 + r) * 136 + wc * 64 + n * 16 + cl] = (s16)f2b(v);
          }
        }
      }
    }
    __syncthreads();
#pragma unroll
    for (int it = 0; it < 2; ++it) {
      int idx = it * 256 + t;
      int lr = idx >> 4, slot = idx & 15;
      *(uint4*)(C + (size_t)(row0 + P * 32 + lr) * N + col0 + slot * 8) =
          *(const uint4*)(Cs + lr * 136 + slot * 8);
    }
  }
}

// ---------------- MFMA GEMM + bias + residual + LayerNorm (N=256) ----------
// R(M,256) <- LN( X(M,K) @ W(256,K)^T + bias + R ). 128 rows/block, 512 thr.
// Counted-vmcnt 2-phase K-loop (3 loads/stage -> vmcnt(3)).
__global__ __launch_bounds__(512) void mfma_gemm_resln(const u16* __restrict__ X,
                                                       const u16* __restrict__ W,
                                                       const float* __restrict__ bias,
                                                       u16* __restrict__ R,
                                                       const float* __restrict__ lnw,
                                                       const float* __restrict__ lnb,
                                                       int K) {
  __shared__ s16 smem[24576];   // A0|A1 (4096 each) | B0|B1 (8192 each)
  __shared__ float pls[32][4][2];
  s16* A0 = smem;        s16* A1 = smem + 4096;
  s16* B0 = smem + 8192; s16* B1 = smem + 16384;
  int t = threadIdx.x;
  int wave = t >> 6, lane = t & 63;
  int wr = wave >> 2, wc = wave & 3;
  int row0 = blockIdx.x * 128;
  int kc = (lane >> 4) & 3, rr = lane & 15;
  const u16* Xp = X + (size_t)(row0 + wave * 16 + rr) * K + kc * 8;
  const u16* Wp0 = W + (size_t)(wave * 16 + rr) * K + kc * 8;
  const u16* Wp1 = W + (size_t)((wave + 8) * 16 + rr) * K + kc * 8;
  f32x4 acc[4][4];
#pragma unroll
  for (int m = 0; m < 4; ++m)
#pragma unroll
    for (int n = 0; n < 4; ++n) acc[m][n] = (f32x4){0.f, 0.f, 0.f, 0.f};

  auto STAGE = [&](s16* a, s16* b, int kidx) {
    int k0 = kidx * 32;
    gload16(Xp + k0, a + wave * 512);
    gload16(Wp0 + k0, b + wave * 512);
    gload16(Wp1 + k0, b + (wave + 8) * 512);
  };
  int nk = K >> 5;
  auto STEP = [&](const s16* a, const s16* b, s16* sa, s16* sb, int ks) {
    if (ks + 1 < nk) asm volatile("s_waitcnt vmcnt(3)" ::: "memory");
    else             asm volatile("s_waitcnt vmcnt(0)" ::: "memory");
    __builtin_amdgcn_sched_barrier(0);
    __builtin_amdgcn_s_barrier();
    __builtin_amdgcn_sched_barrier(0);
    bfrag af[4], bf[4];
#pragma unroll
    for (int m = 0; m < 4; ++m) af[m] = *(const bfrag*)(a + ((wr * 4 + m) * 64 + lane) * 8);
#pragma unroll
    for (int n = 0; n < 4; ++n) bf[n] = *(const bfrag*)(b + ((wc * 4 + n) * 64 + lane) * 8);
    asm volatile("s_waitcnt lgkmcnt(0)" ::: "memory");
    __builtin_amdgcn_sched_barrier(0);
    __builtin_amdgcn_s_barrier();
    __builtin_amdgcn_sched_barrier(0);
    if (ks + 2 < nk) STAGE(sa, sb, ks + 2);
#pragma unroll
    for (int m = 0; m < 4; ++m)
#pragma unroll
      for (int n = 0; n < 4; ++n)
        acc[m][n] = __builtin_amdgcn_mfma_f32_16x16x32_bf16(af[m], bf[n], acc[m][n], 0, 0, 0);
  };

  STAGE(A0, B0, 0);
  STAGE(A1, B1, 1);
  for (int ks = 0; ks < nk; ks += 2) {
    STEP(A0, B0, A0, B0, ks);
    STEP(A1, B1, A1, B1, ks + 1);
  }
  // ---- epilogue ----
  s16* Rs = smem;                 // 32 x 264 = 8448 <= 24576
  int g4 = (lane >> 4) << 2;
  int cl = lane & 15;
  float lw[4], lb[4], bc[4];
#pragma unroll
  for (int n = 0; n < 4; ++n) {
    int col = wc * 64 + n * 16 + cl;
    bc[n] = bias[col]; lw[n] = lnw[col]; lb[n] = lnb[col];
  }
#pragma unroll
  for (int P = 0; P < 4; ++P) {
    bool own = (wr == (P >> 1));
    __syncthreads();
#pragma unroll
    for (int it = 0; it < 2; ++it) {
      int idx = it * 512 + t;
      int lr = idx >> 5, slot = idx & 31;
      *(uint4*)(Rs + lr * 264 + slot * 8) =
          *(const uint4*)(R + (size_t)(row0 + P * 32 + lr) * 256 + slot * 8);
    }
    __syncthreads();
    if (own) {
#pragma unroll
      for (int mm = 0; mm < 2; ++mm) {
        int m = (P & 1) * 2 + mm;
#pragma unroll
        for (int r = 0; r < 4; ++r) {
          int lr = mm * 16 + g4 + r;
          float s = 0.f, s2 = 0.f;
#pragma unroll
          for (int n = 0; n < 4; ++n) {
            float v = acc[m][n][r] + bc[n] +
                      b2f((u16)Rs[lr * 264 + wc * 64 + n * 16 + cl]);
            acc[m][n][r] = v;
            s += v; s2 = fmaf(v, v, s2);
          }
#pragma unroll
          for (int o = 1; o < 16; o <<= 1) { s += __shfl_xor(s, o); s2 += __shfl_xor(s2, o); }
          if (cl == 0) { pls[lr][wc][0] = s; pls[lr][wc][1] = s2; }
        }
      }
    }
    __syncthreads();
    if (own) {
#pragma unroll
      for (int mm = 0; mm < 2; ++mm) {
        int m = (P & 1) * 2 + mm;
#pragma unroll
        for (int r = 0; r < 4; ++r) {
          int lr = mm * 16 + g4 + r;
          float s = pls[lr][0][0] + pls[lr][1][0] + pls[lr][2][0] + pls[lr][3][0];
          float s2 = pls[lr][0][1] + pls[lr][1][1] + pls[lr][2][1] + pls[lr][3][1];
          float mu = s * (1.0f / 256.0f);
          float var = fmaxf(s2 * (1.0f / 256.0f) - mu * mu, 0.0f);
          float rs = rsqrtf(var + 1e-5f);
#pragma unroll
          for (int n = 0; n < 4; ++n) {
            Rs[lr * 264 + wc * 64 + n * 16 + cl] =
                (s16)f2b((acc[m][n][r] - mu) * rs * lw[n] + lb[n]);
          }
        }
      }
    }
    __syncthreads();
#pragma unroll
    for (int it = 0; it < 2; ++it) {
      int idx = it * 512 + t;
      int lr = idx >> 5, slot = idx & 31;
      *(uint4*)(R + (size_t)(row0 + P * 32 + lr) * 256 + slot * 8) =
          *(const uint4*)(Rs + lr * 264 + slot * 8);
    }
  }
}

// ---------------- pooled linear attention (in-place on Q), LDS-staged ------
template <int CROSS, int CAUSAL>
__global__ __launch_bounds__(512) void lin_attn(u16* __restrict__ Q,
                                                const u16* __restrict__ KP) {
  __shared__ u16 qs[64 * 264];
  __shared__ float kpool[16][260];
  int p = blockIdx.x, t = threadIdx.x;
  u16* Qg = Q + (size_t)p * 16384;
#pragma unroll
  for (int i = 0; i < 4; ++i) {
    int idx = i * 512 + t;
    int row = idx >> 5, slot = idx & 31;
    *(uint4*)(qs + row * 264 + slot * 8) = *(const uint4*)(Qg + row * 256 + slot * 8);
  }
  __syncthreads();
  if (CROSS) {
    for (int idx = t; idx < 4096; idx += 512) {
      int s = idx >> 8, d = idx & 255;
      kpool[s][d] = b2f(KP[((size_t)p * 16 + s) * 256 + d]);
    }
  } else {
    for (int idx = t; idx < 4096; idx += 512) {
      int s = idx >> 8, d = idx & 255;
      const u16* b0 = qs + (4 * s) * 264 + d;
      kpool[s][d] = 0.25f * (b2f(b0[0]) + b2f(b0[264]) + b2f(b0[528]) + b2f(b0[792]));
    }
  }
  __syncthreads();
  int h = t >> 6, l = t & 63;
  u16* q = qs + l * 264 + h * 32;
  float qr[32];
#pragma unroll
  for (int e = 0; e < 32; e += 4) {
    ushort4 v = *(const ushort4*)&q[e];
    qr[e] = b2f(v.x); qr[e + 1] = b2f(v.y); qr[e + 2] = b2f(v.z); qr[e + 3] = b2f(v.w);
  }
  float sc[16], mx = -INFINITY;
#pragma unroll
  for (int s = 0; s < 16; ++s) {
    const float* kp = &kpool[s][h * 32];
    float d = 0.f;
#pragma unroll
    for (int e = 0; e < 32; ++e) d = fmaf(qr[e], kp[e], d);
    d *= 0.17677669529663687f;
    if (CAUSAL && s > l) d = -INFINITY;
    sc[s] = d; mx = fmaxf(mx, d);
  }
  float sum = 0.f;
#pragma unroll
  for (int s = 0; s < 16; ++s) { sc[s] = expf(sc[s] - mx); sum += sc[s]; }
  float inv = 1.0f / sum;
  float o[32] = {};
#pragma unroll
  for (int s = 0; s < 16; ++s) {
    float a = sc[s] * inv;
    const float* vp = &kpool[s][h * 32];
#pragma unroll
    for (int e = 0; e < 32; ++e) o[e] = fmaf(a, vp[e], o[e]);
  }
#pragma unroll
  for (int e = 0; e < 32; e += 4) {
    ushort4 v;
    v.x = f2b(o[e]); v.y = f2b(o[e + 1]); v.z = f2b(o[e + 2]); v.w = f2b(o[e + 3]);
    *(ushort4*)&q[e] = v;
  }
  __syncthreads();
#pragma unroll
  for (int i = 0; i < 4; ++i) {
    int idx = i * 512 + t;
    int row = idx >> 5, slot = idx & 31;
    *(uint4*)(Qg + row * 256 + slot * 8) = *(const uint4*)(qs + row * 264 + slot * 8);
  }
}

// ---------------- plain LayerNorm (in place), bf16 -------------------------
__global__ __launch_bounds__(256) void ln_bf(u16* __restrict__ X,
                                             const float* __restrict__ w,
                                             const float* __restrict__ b) {
  int lane = threadIdx.x & 63, wv = threadIdx.x >> 6;
  size_t row = (size_t)blockIdx.x * 4 + wv;
  size_t off = row * 256 + lane * 4;
  ushort4 xv = *(const ushort4*)(X + off);
  float v0 = b2f(xv.x), v1 = b2f(xv.y), v2 = b2f(xv.z), v3 = b2f(xv.w);
  float s = v0 + v1 + v2 + v3;
  float s2 = v0 * v0 + v1 * v1 + v2 * v2 + v3 * v3;
#pragma unroll
  for (int o = 32; o; o >>= 1) { s += __shfl_xor(s, o); s2 += __shfl_xor(s2, o); }
  float mu = s * (1.0f / 256.0f);
  float var = fmaxf(s2 * (1.0f / 256.0f) - mu * mu, 0.0f);
  float rs = rsqrtf(var + 1e-5f);
  float4 w4 = *(const float4*)(w + lane * 4);
  float4 b4 = *(const float4*)(b + lane * 4);
  ushort4 o4;
  o4.x = f2b((v0 - mu) * rs * w4.x + b4.x);
  o4.y = f2b((v1 - mu) * rs * w4.y + b4.y);
  o4.z = f2b((v2 - mu) * rs * w4.z + b4.z);
  o4.w = f2b((v3 - mu) * rs * w4.w + b4.w);
  *(ushort4*)(X + off) = o4;
}

// ---------------- pool over j (4:1) ----------------------------------------
__global__ void pool_bf(const u16* __restrict__ A, u16* __restrict__ P) {
  int r = blockIdx.x, d = threadIdx.x;
  int g = r >> 4, s = r & 15;
  const u16* src = A + ((size_t)g * 64 + 4 * (size_t)s) * 256 + d;
  float v = 0.25f * (b2f(src[0]) + b2f(src[256]) + b2f(src[512]) + b2f(src[768]));
  P[(size_t)r * 256 + d] = f2b(v);
}

// ---------------- mean over j + final projection + slice -------------------
__global__ __launch_bounds__(256) void mean_proj_bf(const u16* __restrict__ X,
                                                    const float* __restrict__ pw,
                                                    const float* __restrict__ pb,
                                                    float* __restrict__ out) {
  int bid = blockIdx.x;
  int b = bid >> 5, ii = bid & 31;
  int i = 32 + ii;
  __shared__ float md[256];
  int d = threadIdx.x;
  const u16* base = X + ((size_t)b * 64 + i) * 64 * 256 + d;
  float s = 0.f;
  for (int j = 0; j < 64; ++j) s += b2f(base[(size_t)j * 256]);
  md[d] = s * (1.0f / 64.0f);
  __syncthreads();
  if (d < 64) {
    float acc = pb[d];
    const float* wr = pw + d * 256;
    for (int k = 0; k < 256; ++k) acc = fmaf(md[k], wr[k], acc);
    out[((size_t)b * 32 + ii) * 64 + d] = acc;
  }
}

// ---------------------------------------------------------------------------
extern "C" void kernel_launch(void* const* d_in, const int* in_sizes, int n_in,
                              void* d_out, int out_size, void* d_ws, size_t ws_size,
                              hipStream_t stream) {
  (void)in_sizes; (void)out_size;
  if (n_in < 50) return;

  const float* x_enc = (const float*)d_in[0];
  const float* x_dec = (const float*)d_in[1];
  const float* enc_sproj_w = (const float*)d_in[2];
  const float* enc_sproj_b = (const float*)d_in[3];
  const float* enc_scproj_w = (const float*)d_in[4];
  const float* enc_scproj_b = (const float*)d_in[5];
  const float* enc_tok_w = (const float*)d_in[6];
  const float* enc_tok_b = (const float*)d_in[7];
  const float* dec_sproj_w = (const float*)d_in[8];
  const float* dec_sproj_b = (const float*)d_in[9];
  const float* dec_scproj_w = (const float*)d_in[10];
  const float* dec_scproj_b = (const float*)d_in[11];
  const float* dec_tok_w = (const float*)d_in[12];
  const float* dec_tok_b = (const float*)d_in[13];
  const float* e_Wq = (const float*)d_in[14];
  const float* e_bq = (const float*)d_in[15];
  const float* e_Wo = (const float*)d_in[16];
  const float* e_bo = (const float*)d_in[17];
  const float* e_c1w = (const float*)d_in[18];
  const float* e_c1b = (const float*)d_in[19];
  const float* e_c2w = (const float*)d_in[20];
  const float* e_c2b = (const float*)d_in[21];
  const float* e_ln1w = (const float*)d_in[22];
  const float* e_ln1b = (const float*)d_in[23];
  const float* e_ln2w = (const float*)d_in[24];
  const float* e_ln2b = (const float*)d_in[25];
  const float* enc_norm_w = (const float*)d_in[26];
  const float* enc_norm_b = (const float*)d_in[27];
  const float* d_sWq = (const float*)d_in[28];
  const float* d_sbq = (const float*)d_in[29];
  const float* d_sWo = (const float*)d_in[30];
  const float* d_sbo = (const float*)d_in[31];
  const float* d_cWq = (const float*)d_in[32];
  const float* d_cbq = (const float*)d_in[33];
  const float* d_cWo = (const float*)d_in[34];
  const float* d_cbo = (const float*)d_in[35];
  const float* d_c1w = (const float*)d_in[36];
  const float* d_c1b = (const float*)d_in[37];
  const float* d_c2w = (const float*)d_in[38];
  const float* d_c2b = (const float*)d_in[39];
  const float* d_ln1w = (const float*)d_in[40];
  const float* d_ln1b = (const float*)d_in[41];
  const float* d_ln2w = (const float*)d_in[42];
  const float* d_ln2b = (const float*)d_in[43];
  const float* d_ln3w = (const float*)d_in[44];
  const float* d_ln3b = (const float*)d_in[45];
  const float* dec_norm_w = (const float*)d_in[46];
  const float* dec_norm_b = (const float*)d_in[47];
  const float* proj_w = (const float*)d_in[48];
  const float* proj_b = (const float*)d_in[49];

  // ---- workspace layout ----
  const size_t ACT = 16777216;    // 65536*256
  const size_t POOLE = 4194304;   // 16384*256
  const size_t WBN = 3538944;     // bf16 weight pool elements
  size_t base_need = (3 * ACT + 2 * POOLE + WBN) * 2 +
                     (size_t)(16384 + 147456 + 98304 + 65536) * 4;
  if (ws_size < base_need) {
    ws_signal<<<1, 1, 0, stream>>>((float*)d_out, (float)(ws_size >> 20));
    return;
  }
  char* wsb = (char*)d_ws;
  u16* A_enc = (u16*)wsb;  wsb += ACT * 2;
  u16* A_dec = (u16*)wsb;  wsb += ACT * 2;
  u16* T1 = (u16*)wsb;     wsb += ACT * 2;   // attn scratch
  u16* PA = (u16*)wsb;     wsb += POOLE * 2;
  u16* PK = (u16*)wsb;     wsb += POOLE * 2;
  u16* WB = (u16*)wsb;     wsb += WBN * 2;
  float* PE = (float*)wsb;  wsb += 16384 * 4;
  float* EH1 = (float*)wsb; wsb += 147456 * 4;
  float* EH2 = (float*)wsb; wsb += 98304 * 4;
  float* EH3 = (float*)wsb; wsb += 65536 * 4;

  // adaptive FFN hidden buffer: prefer one full-width pass
  int hf_rows = 16384;
  u16* HF = T1;  // default: alias attn scratch (dead during FFN)
  if (ws_size >= base_need + (size_t)65536 * 1024 * 2) {
    hf_rows = 65536; HF = (u16*)wsb;
  } else if (ws_size >= base_need + (size_t)32768 * 1024 * 2) {
    hf_rows = 32768; HF = (u16*)wsb;
  }

  // bf16 weight pool offsets (elements)
  u16* eWq = WB;                    // 3 x 65536
  u16* eWeff = WB + 196608;         // 3 x 65536
  u16* eC1 = WB + 393216;           // 3 x 262144
  u16* eC2 = WB + 1179648;          // 3 x 262144
  u16* dB = WB + 1966080;
  u16* dsWq = dB;                   // 2 x 65536
  u16* dsWeff = dB + 131072;        // 2 x 65536
  u16* dcWq = dB + 262144;          // 2 x 65536
  u16* dcWeff = dB + 393216;        // 2 x 65536
  u16* dC1 = dB + 524288;           // 2 x 262144
  u16* dC2 = dB + 1048576;          // 2 x 262144

  // ---- weight conversion ----
  cvt_bf<<<768, 256, 0, stream>>>(e_Wq, eWq, 196608);
  cvt_bf<<<3072, 256, 0, stream>>>(e_c1w, eC1, 786432);
  cvt_bf<<<3072, 256, 0, stream>>>(e_c2w, eC2, 786432);
  cvt_bf<<<512, 256, 0, stream>>>(d_sWq, dsWq, 131072);
  cvt_bf<<<512, 256, 0, stream>>>(d_cWq, dcWq, 131072);
  cvt_bf<<<2048, 256, 0, stream>>>(d_c1w, dC1, 524288);
  cvt_bf<<<2048, 256, 0, stream>>>(d_c2w, dC2, 524288);
  for (int i = 0; i < 3; ++i)
    weff_bf<<<256, 256, 0, stream>>>(e_Wo + (size_t)i * 131072, eWeff + (size_t)i * 65536);
  for (int i = 0; i < 2; ++i) {
    weff_bf<<<256, 256, 0, stream>>>(d_sWo + (size_t)i * 131072, dsWeff + (size_t)i * 65536);
    weff_bf<<<256, 256, 0, stream>>>(d_cWo + (size_t)i * 131072, dcWeff + (size_t)i * 65536);
  }

  pe_kernel<<<64, 256, 0, stream>>>(PE);

  // ---- encoder embedding ----
  conv_sproj<<<dim3(96, 16), 96, 0, stream>>>(x_enc, enc_sproj_w, enc_sproj_b, EH1);
  conv_scproj_t<<<dim3(64, 16), 96, 0, stream>>>(EH1, enc_scproj_w, enc_scproj_b, EH2);
  conv_scproj_s<<<dim3(64, 16), 64, 0, stream>>>(EH2, enc_scproj_w, enc_scproj_b, EH3);
  tok_embed<<<1024, 256, 0, stream>>>(EH3, enc_tok_w, enc_tok_b, PE, A_enc);

  // ---- encoder layers ----
  for (int i = 0; i < 3; ++i) {
    mfma_gemm<0, 2><<<1024, 256, 0, stream>>>(A_enc, eWq + (size_t)i * 65536,
                                              e_bq + i * 256, T1, 256, 256, 512);
    lin_attn<0, 0><<<1024, 512, 0, stream>>>(T1, nullptr);
    mfma_gemm_resln<<<512, 512, 0, stream>>>(T1, eWeff + (size_t)i * 65536, e_bo + i * 256,
                                             A_enc, e_ln1w + i * 256, e_ln1b + i * 256, 256);
    for (int m0 = 0; m0 < 65536; m0 += hf_rows) {
      u16* Xc = A_enc + (size_t)m0 * 256;
      int nby = hf_rows / 128;
      mfma_gemm<1, 8><<<8 * nby, 256, 0, stream>>>(
          Xc, eC1 + (size_t)i * 262144, e_c1b + i * 1024, HF, 1024, 256, nby);
      mfma_gemm_resln<<<nby, 512, 0, stream>>>(
          HF, eC2 + (size_t)i * 262144, e_c2b + i * 256, Xc,
          e_ln2w + i * 256, e_ln2b + i * 256, 1024);
    }
  }
  ln_bf<<<16384, 256, 0, stream>>>(A_enc, enc_norm_w, enc_norm_b);
  pool_bf<<<16384, 256, 0, stream>>>(A_enc, PA);

  // ---- decoder embedding ----
  conv_sproj<<<dim3(96, 16), 96, 0, stream>>>(x_dec, dec_sproj_w, dec_sproj_b, EH1);
  conv_scproj_t<<<dim3(64, 16), 96, 0, stream>>>(EH1, dec_scproj_w, dec_scproj_b, EH2);
  conv_scproj_s<<<dim3(64, 16), 64, 0, stream>>>(EH2, dec_scproj_w, dec_scproj_b, EH3);
  tok_embed<<<1024, 256, 0, stream>>>(EH3, dec_tok_w, dec_tok_b, PE, A_dec);

  // ---- decoder layers ----
  for (int i = 0; i < 2; ++i) {
    mfma_gemm<0, 2><<<1024, 256, 0, stream>>>(A_dec, dsWq + (size_t)i * 65536,
                                              d_sbq + i * 256, T1, 256, 256, 512);
    lin_attn<0, 1><<<1024, 512, 0, stream>>>(T1, nullptr);
    mfma_gemm_resln<<<512, 512, 0, stream>>>(T1, dsWeff + (size_t)i * 65536, d_sbo + i * 256,
                                             A_dec, d_ln1w + i * 256, d_ln1b + i * 256, 256);
    mfma_gemm<0, 2><<<1024, 256, 0, stream>>>(A_dec, dcWq + (size_t)i * 65536,
                                              d_cbq + i * 256, T1, 256, 256, 512);
    mfma_gemm<0, 2><<<256, 256, 0, stream>>>(PA, dcWq + (size_t)i * 65536,
                                             d_cbq + i * 256, PK, 256, 256, 128);
    lin_attn<1, 0><<<1024, 512, 0, stream>>>(T1, PK);
    mfma_gemm_resln<<<512, 512, 0, stream>>>(T1, dcWeff + (size_t)i * 65536, d_cbo + i * 256,
                                             A_dec, d_ln2w + i * 256, d_ln2b + i * 256, 256);
    for (int m0 = 0; m0 < 65536; m0 += hf_rows) {
      u16* Xc = A_dec + (size_t)m0 * 256;
      int nby = hf_rows / 128;
      mfma_gemm<1, 8><<<8 * nby, 256, 0, stream>>>(
          Xc, dC1 + (size_t)i * 262144, d_c1b + i * 1024, HF, 1024, 256, nby);
      mfma_gemm_resln<<<nby, 512, 0, stream>>>(
          HF, dC2 + (size_t)i * 262144, d_c2b + i * 256, Xc,
          d_ln3w + i * 256, d_ln3b + i * 256, 1024);
    }
  }
  ln_bf<<<16384, 256, 0, stream>>>(A_dec, dec_norm_w, dec_norm_b);

  mean_proj_bf<<<512, 256, 0, stream>>>(A_dec, proj_w, proj_b, (float*)d_out);
}